// Round 3
// baseline (428.633 us; speedup 1.0000x reference)
//
#include <hip/hip_runtime.h>
#include <math.h>

#define Bz 32
#define Lz 2048
#define Hz 768
#define Tz 12
#define Ez 7
#define EMPTYIDX 6
#define NCOL 24          // T*2 logit columns per batch
#define LCHUNK 128
#define NCHUNK 16        // Lz / LCHUNK

// ---------------- kernel 1a: cW partial dots, H split across blocks ----------
// grid = Ez(7) * ZC(3) * HC(16) = 336 blocks, 256 threads.
// Binning of (b,t) by e is done block-locally (384-entry scan, ~1.5KB reads),
// killing the separate compaction kernel. Each block owns a 48h x 256z slab
// of W[e] in registers; ctx rows come in via uniform (scalar) loads; partials
// atomicAdd into cW (zeroed via hipMemsetAsync).
#define K1A_ZC 3
#define K1A_HB 48
#define K1A_HC 16
__global__ void k1a_cw(const float* __restrict__ seq, const float* __restrict__ W,
                       const int* __restrict__ turns, const int* __restrict__ midx,
                       float* __restrict__ cW) {
    int bx = blockIdx.x;
    int e  = bx % Ez;
    int zc = (bx / Ez) % K1A_ZC;
    int hc = bx / (Ez * K1A_ZC);           // 0..15
    int z  = zc * 256 + threadIdx.x;       // 0..767
    int h0 = hc * K1A_HB;
    int tid = threadIdx.x;

    __shared__ int itemsS[Bz * Tz];
    __shared__ int cntS;
    if (tid == 0) cntS = 0;
    __syncthreads();
    for (int i = tid; i < Bz * Tz; i += 256) {
        int ei = midx[i];
        ei = min(max(ei, 0), Ez - 1);
        if (ei == e) {
            int p = atomicAdd(&cntS, 1);
            itemsS[p] = i;
        }
    }
    __syncthreads();
    int cnt = cntS;

    const float* Wb = W + ((size_t)e * Hz + h0) * Hz + z;
    float w[K1A_HB];
#pragma unroll
    for (int j = 0; j < K1A_HB; ++j) w[j] = Wb[(size_t)j * Hz];

    for (int n = 0; n < cnt; ++n) {
        int i  = itemsS[n];                // block-uniform
        int b  = i / Tz;
        int st = turns[2 * i];
        st = min(max(st, 0), Lz - 1);
        const float* c = seq + ((size_t)(b * Lz + st)) * Hz + h0;  // uniform -> s_load
        float acc = 0.f;
#pragma unroll
        for (int j = 0; j < K1A_HB; ++j) acc = fmaf(c[j], w[j], acc);
        atomicAdd(&cW[(size_t)i * Hz + z], acc);
    }
}

// ---------------- kernel 1b: v = cW * spanw (elementwise) --------------------
__global__ void k1b_v(const float* __restrict__ cW, const float* __restrict__ spanw,
                      const int* __restrict__ midx, float* __restrict__ v) {
    int idx = blockIdx.x * 256 + threadIdx.x;   // 384*768 = 294912
    int i = idx / Hz;
    int z = idx - i * Hz;
    int e = midx[i];
    e = min(max(e, 0), Ez - 1);
    float cw = cW[idx];
    int b = i / Tz, t = i - b * Tz;
    size_t vb = ((size_t)(b * NCOL + t * 2)) * Hz + z;
    v[vb]      = cw * spanw[(e * Hz + z) * 2 + 0];
    v[vb + Hz] = cw * spanw[(e * Hz + z) * 2 + 1];
}

// ---------------- kernel 2: logits GEMM + block logsumexp partials -----------
// grid = Bz*NCHUNK = 512 blocks, 256 threads, BK=64.
// m97-style 2-barrier K-loop: next tile's global loads are issued right after
// the barrier and stay in flight across compute (~1536 cyc/wave covers ~900
// cyc HBM latency); regs -> LDS after the second barrier.
// Thread tile: rows {rg, rg+32, rg+64, rg+96}, cols cg*3..cg*3+2; row stride
// ATS=68 floats (68 mod 32 = 4) makes concurrent b128 reads tile all 32 banks.
#define BK 64
#define ATS (BK + 4)
__global__ void k2_logits(const float* __restrict__ seq, const float* __restrict__ v,
                          float* __restrict__ pm, float* __restrict__ ps) {
    int bx = blockIdx.x;
    int b  = bx / NCHUNK;
    int ch = bx % NCHUNK;
    int l0 = ch * LCHUNK;
    int tid = threadIdx.x;
    int rg = tid >> 3;                     // 0..31 -> rows rg + 32*r
    int cg = tid & 7;                      // 0..7  -> cols cg*3..cg*3+2
    __shared__ float at[LCHUNK][ATS];      // 34.8 KB
    __shared__ float vt[NCOL][ATS];        // 6.5 KB
    __shared__ float red_m[NCOL][33];
    __shared__ float red_s[NCOL][33];
    float acc[4][3];
#pragma unroll
    for (int r = 0; r < 4; ++r)
#pragma unroll
        for (int j = 0; j < 3; ++j) acc[r][j] = 0.f;

    const float* A = seq + ((size_t)b * Lz + l0) * Hz;
    const float* V = v + (size_t)b * NCOL * Hz;

    int ar = tid >> 4, ac4 = tid & 15;     // A-stage coords (with +p*256 offset)
    float4 ra[8];
    float4 rv0, rv1;
    // prologue: prefetch tile 0 into registers
#pragma unroll
    for (int p = 0; p < 8; ++p) {
        int j = tid + p * 256, r = j >> 4, c4 = j & 15;
        ra[p] = *(const float4*)&A[(size_t)r * Hz + c4 * 4];
    }
    rv0 = *(const float4*)&V[(size_t)(tid >> 4) * Hz + (tid & 15) * 4];
    if (tid < 128) {
        int j = tid + 256;
        rv1 = *(const float4*)&V[(size_t)(j >> 4) * Hz + (j & 15) * 4];
    }

    for (int k0 = 0; k0 < Hz; k0 += BK) {
        // write prefetched tile into LDS
#pragma unroll
        for (int p = 0; p < 8; ++p) {
            int j = tid + p * 256, r = j >> 4, c4 = j & 15;
            *(float4*)&at[r][c4 * 4] = ra[p];
        }
        *(float4*)&vt[tid >> 4][(tid & 15) * 4] = rv0;
        if (tid < 128) {
            int j = tid + 256;
            *(float4*)&vt[j >> 4][(j & 15) * 4] = rv1;
        }
        __syncthreads();
        // issue next tile's loads — stay in flight across compute
        if (k0 + BK < Hz) {
#pragma unroll
            for (int p = 0; p < 8; ++p) {
                int j = tid + p * 256, r = j >> 4, c4 = j & 15;
                ra[p] = *(const float4*)&A[(size_t)r * Hz + k0 + BK + c4 * 4];
            }
            rv0 = *(const float4*)&V[(size_t)(tid >> 4) * Hz + k0 + BK + (tid & 15) * 4];
            if (tid < 128) {
                int j = tid + 256;
                rv1 = *(const float4*)&V[(size_t)(j >> 4) * Hz + k0 + BK + (j & 15) * 4];
            }
        }
        // compute from LDS
#pragma unroll
        for (int kk = 0; kk < BK; kk += 4) {
            float4 a0 = *(const float4*)&at[rg +  0][kk];
            float4 a1 = *(const float4*)&at[rg + 32][kk];
            float4 a2 = *(const float4*)&at[rg + 64][kk];
            float4 a3 = *(const float4*)&at[rg + 96][kk];
            float4 v0 = *(const float4*)&vt[cg * 3 + 0][kk];
            float4 v1 = *(const float4*)&vt[cg * 3 + 1][kk];
            float4 v2 = *(const float4*)&vt[cg * 3 + 2][kk];
#define DOT(ACC, AV, VV) ACC = fmaf(AV.w, VV.w, fmaf(AV.z, VV.z, fmaf(AV.y, VV.y, fmaf(AV.x, VV.x, ACC))))
            DOT(acc[0][0], a0, v0); DOT(acc[0][1], a0, v1); DOT(acc[0][2], a0, v2);
            DOT(acc[1][0], a1, v0); DOT(acc[1][1], a1, v1); DOT(acc[1][2], a1, v2);
            DOT(acc[2][0], a2, v0); DOT(acc[2][1], a2, v1); DOT(acc[2][2], a2, v2);
            DOT(acc[3][0], a3, v0); DOT(acc[3][1], a3, v1); DOT(acc[3][2], a3, v2);
#undef DOT
        }
        __syncthreads();
    }
    (void)ar; (void)ac4;
    // local online-softmax over this thread's 4 rows, combine over 32 row-groups
#pragma unroll
    for (int j = 0; j < 3; ++j) {
        int c = cg * 3 + j;
        float m = fmaxf(fmaxf(acc[0][j], acc[1][j]), fmaxf(acc[2][j], acc[3][j]));
        float s = expf(acc[0][j] - m) + expf(acc[1][j] - m) +
                  expf(acc[2][j] - m) + expf(acc[3][j] - m);
        red_m[c][rg] = m;
        red_s[c][rg] = s;
    }
    __syncthreads();
    if (tid < NCOL) {
        int c = tid;
        float m = red_m[c][0];
        for (int r = 1; r < 32; ++r) m = fmaxf(m, red_m[c][r]);
        float s = 0.f;
        for (int r = 0; r < 32; ++r) s += red_s[c][r] * expf(red_m[c][r] - m);
        pm[((size_t)b * NCOL + c) * NCHUNK + ch] = m;
        ps[((size_t)b * NCOL + c) * NCHUNK + ch] = s;
    }
}

// ---------------- kernel 3: picked logits (dot at the target row) ----------------
__global__ void k3_picked(const float* __restrict__ seq, const float* __restrict__ v,
                          const int* __restrict__ kps, float* __restrict__ picked) {
    int i = blockIdx.x;                    // 0..383
    int b = i / Tz, t = i % Tz;
    int lane = threadIdx.x;                // 64
    for (int k = 0; k < 2; ++k) {
        int tgt  = kps[2 * i + k];
        int safe = min(max(tgt, 0), Lz - 1);
        const float* srow = seq + ((size_t)b * Lz + safe) * Hz;
        const float* vcol = v + ((size_t)(b * NCOL + t * 2 + k)) * Hz;
        float sum = 0.f;
#pragma unroll
        for (int q = 0; q < Hz / 64; ++q) {
            int z = lane + q * 64;
            sum = fmaf(srow[z], vcol[z], sum);
        }
        for (int o = 32; o > 0; o >>= 1) sum += __shfl_down(sum, o, 64);
        if (lane == 0) picked[b * NCOL + t * 2 + k] = sum;
    }
}

// ---------------- kernel 4: combine partials -> ce -> masked-mean loss ----------------
__global__ void k4_final(const int* __restrict__ midx, const int* __restrict__ turns,
                         const int* __restrict__ kps,
                         const float* __restrict__ pm, const float* __restrict__ ps,
                         const float* __restrict__ picked, float* __restrict__ out) {
    int tid = threadIdx.x;                 // 384 threads, one per (b,t)
    int i = tid;
    int b = i / Tz, t = i % Tz;
    int e = midx[i];
    float modm  = (e != EMPTYIDX) ? 1.f : 0.f;
    float tmask = (turns[2 * i] >= 0) ? 1.f : 0.f;
    float ce[2];
#pragma unroll
    for (int k = 0; k < 2; ++k) {
        int c = t * 2 + k;
        const float* pmr = pm + ((size_t)b * NCOL + c) * NCHUNK;
        const float* psr = ps + ((size_t)b * NCOL + c) * NCHUNK;
        float m = pmr[0];
        for (int chn = 1; chn < NCHUNK; ++chn) m = fmaxf(m, pmr[chn]);
        float s = 0.f;
        for (int chn = 0; chn < NCHUNK; ++chn) s += psr[chn] * expf(pmr[chn] - m);
        float lse = m + logf(s);
        int tgt = kps[2 * i + k];
        ce[k] = (tgt >= 0) ? (lse - picked[b * NCOL + c]) : 0.f;
    }
    float contrib = 0.5f * (ce[0] + ce[1]) * modm * tmask;

    __shared__ float wsum[6], wmask[6];
    float sl = contrib, sm = tmask;
    for (int o = 32; o > 0; o >>= 1) {
        sl += __shfl_down(sl, o, 64);
        sm += __shfl_down(sm, o, 64);
    }
    int w = tid >> 6, lane = tid & 63;
    if (lane == 0) { wsum[w] = sl; wmask[w] = sm; }
    __syncthreads();
    if (tid == 0) {
        float a = 0.f, mk = 0.f;
        for (int ww = 0; ww < 6; ++ww) { a += wsum[ww]; mk += wmask[ww]; }
        out[0] = a / mk;
    }
}

extern "C" void kernel_launch(void* const* d_in, const int* in_sizes, int n_in,
                              void* d_out, int out_size, void* d_ws, size_t ws_size,
                              hipStream_t stream) {
    const float* seq   = (const float*)d_in[0];  // (32,2048,768)
    const float* W     = (const float*)d_in[1];  // (7,768,768)
    const float* spanw = (const float*)d_in[2];  // (7,768,2)
    const int*   turns = (const int*)d_in[3];    // (32,12,2)
    const int*   kps   = (const int*)d_in[4];    // (32,12,2)
    const int*   midx  = (const int*)d_in[5];    // (32,12)
    float* out = (float*)d_out;

    char* ws = (char*)d_ws;
    float* cW     = (float*)(ws + 0);                  // 384*768 f32   = 1,179,648 B
    float* v      = (float*)(ws + 1179648);            // 32*24*768 f32 = 2,359,296 B
    float* pm     = (float*)(ws + 1179648 + 2359296);               // 49,152 B
    float* ps     = (float*)(ws + 1179648 + 2359296 + 49152);       // 49,152 B
    float* picked = (float*)(ws + 1179648 + 2359296 + 98304);       // 3,072 B

    hipMemsetAsync(cW, 0, (size_t)384 * Hz * sizeof(float), stream);
    hipLaunchKernelGGL(k1a_cw, dim3(Ez * K1A_ZC * K1A_HC), dim3(256), 0, stream,
                       seq, W, turns, midx, cW);
    hipLaunchKernelGGL(k1b_v, dim3((384 * Hz) / 256), dim3(256), 0, stream,
                       cW, spanw, midx, v);
    hipLaunchKernelGGL(k2_logits, dim3(Bz * NCHUNK), dim3(256), 0, stream, seq, v, pm, ps);
    hipLaunchKernelGGL(k3_picked, dim3(Bz * Tz), dim3(64), 0, stream, seq, v, kps, picked);
    hipLaunchKernelGGL(k4_final, dim3(1), dim3(Bz * Tz), 0, stream,
                       midx, turns, kps, pm, ps, picked, out);
}

// Round 4
// 420.466 us; speedup vs baseline: 1.0194x; 1.0194x over previous
//
#include <hip/hip_runtime.h>
#include <math.h>

#define Bz 32
#define Lz 2048
#define Hz 768
#define Tz 12
#define Ez 7
#define EMPTYIDX 6
#define NCOL 24          // T*2 logit columns per batch
#define LCHUNK 128
#define NCHUNK 16        // Lz / LCHUNK

// ---------------- kernel 1a: cW partial dots, H split across blocks ----------
#define K1A_ZC 3
#define K1A_HB 48
#define K1A_HC 16
__global__ void k1a_cw(const float* __restrict__ seq, const float* __restrict__ W,
                       const int* __restrict__ turns, const int* __restrict__ midx,
                       float* __restrict__ cW) {
    int bx = blockIdx.x;
    int e  = bx % Ez;
    int zc = (bx / Ez) % K1A_ZC;
    int hc = bx / (Ez * K1A_ZC);           // 0..15
    int z  = zc * 256 + threadIdx.x;       // 0..767
    int h0 = hc * K1A_HB;
    int tid = threadIdx.x;

    __shared__ int itemsS[Bz * Tz];
    __shared__ int cntS;
    if (tid == 0) cntS = 0;
    __syncthreads();
    for (int i = tid; i < Bz * Tz; i += 256) {
        int ei = midx[i];
        ei = min(max(ei, 0), Ez - 1);
        if (ei == e) {
            int p = atomicAdd(&cntS, 1);
            itemsS[p] = i;
        }
    }
    __syncthreads();
    int cnt = cntS;

    const float* Wb = W + ((size_t)e * Hz + h0) * Hz + z;
    float w[K1A_HB];
#pragma unroll
    for (int j = 0; j < K1A_HB; ++j) w[j] = Wb[(size_t)j * Hz];

    for (int n = 0; n < cnt; ++n) {
        int i  = itemsS[n];                // block-uniform
        int b  = i / Tz;
        int st = turns[2 * i];
        st = min(max(st, 0), Lz - 1);
        const float* c = seq + ((size_t)(b * Lz + st)) * Hz + h0;  // uniform -> s_load
        float acc = 0.f;
#pragma unroll
        for (int j = 0; j < K1A_HB; ++j) acc = fmaf(c[j], w[j], acc);
        atomicAdd(&cW[(size_t)i * Hz + z], acc);
    }
}

// ---------------- kernel 1b: v = cW * spanw (elementwise) --------------------
__global__ void k1b_v(const float* __restrict__ cW, const float* __restrict__ spanw,
                      const int* __restrict__ midx, float* __restrict__ v) {
    int idx = blockIdx.x * 256 + threadIdx.x;   // 384*768 = 294912
    int i = idx / Hz;
    int z = idx - i * Hz;
    int e = midx[i];
    e = min(max(e, 0), Ez - 1);
    float cw = cW[idx];
    int b = i / Tz, t = i - b * Tz;
    size_t vb = ((size_t)(b * NCOL + t * 2)) * Hz + z;
    v[vb]      = cw * spanw[(e * Hz + z) * 2 + 0];
    v[vb + Hz] = cw * spanw[(e * Hz + z) * 2 + 1];
}

// ---------------- kernel 2: logits GEMM + block logsumexp partials -----------
// grid = Bz*NCHUNK = 512 blocks, 128 threads, BK=64.
// Thread tile 4 rows x 6 cols (rows {rg,rg+32,rg+64,rg+96}, cols colg*6..+5):
// 10 ds_read_b128 feed 96 FMAs per kk-step (was 7:48) -> LDS-pipe time x0.71.
// Register prefetch of the next K-tile; __launch_bounds__(128,2) lifts the
// VGPR cap to 256 so the ~140-VGPR working set does NOT spill (round-3 bug:
// 64-VGPR target spilled ra[] -> 197 MB scratch writes).
#define BK 64
#define ATS (BK + 4)     // stride 68: concurrent rows start at banks 4r%32, 2-way = free
#define K2_T 128
__global__ void __launch_bounds__(K2_T, 2)
k2_logits(const float* __restrict__ seq, const float* __restrict__ v,
          float* __restrict__ pm, float* __restrict__ ps) {
    int bx = blockIdx.x;
    int b  = bx / NCHUNK;
    int ch = bx % NCHUNK;
    int l0 = ch * LCHUNK;
    int tid = threadIdx.x;
    int rg   = tid >> 2;                   // 0..31 -> rows rg + 32*r
    int colg = tid & 3;                    // 0..3  -> cols colg*6..colg*6+5
    __shared__ float at[LCHUNK][ATS];      // 34.8 KB
    __shared__ float vt[NCOL][ATS];        // 6.5 KB
    __shared__ float red_m[NCOL][33];
    __shared__ float red_s[NCOL][33];
    float acc[4][6];
#pragma unroll
    for (int r = 0; r < 4; ++r)
#pragma unroll
        for (int j = 0; j < 6; ++j) acc[r][j] = 0.f;

    const float* A = seq + ((size_t)b * Lz + l0) * Hz;
    const float* V = v + (size_t)b * NCOL * Hz;

    float4 ra[16];                         // 128x64 A-tile: 2048 float4 / 128 thr
    float4 rv[3];                          // 24x64 V-tile:   384 float4 / 128 thr
    // prologue: prefetch tile 0
#pragma unroll
    for (int p = 0; p < 16; ++p) {
        int j = tid + p * K2_T, r = j >> 4, c4 = j & 15;
        ra[p] = *(const float4*)&A[(size_t)r * Hz + c4 * 4];
    }
#pragma unroll
    for (int p = 0; p < 3; ++p) {
        int j = tid + p * K2_T, c = j >> 4, q = j & 15;
        rv[p] = *(const float4*)&V[(size_t)c * Hz + q * 4];
    }

    for (int k0 = 0; k0 < Hz; k0 += BK) {
        // write prefetched tile into LDS
#pragma unroll
        for (int p = 0; p < 16; ++p) {
            int j = tid + p * K2_T, r = j >> 4, c4 = j & 15;
            *(float4*)&at[r][c4 * 4] = ra[p];
        }
#pragma unroll
        for (int p = 0; p < 3; ++p) {
            int j = tid + p * K2_T, c = j >> 4, q = j & 15;
            *(float4*)&vt[c][q * 4] = rv[p];
        }
        __syncthreads();
        // issue next tile's global loads — in flight across compute
        if (k0 + BK < Hz) {
#pragma unroll
            for (int p = 0; p < 16; ++p) {
                int j = tid + p * K2_T, r = j >> 4, c4 = j & 15;
                ra[p] = *(const float4*)&A[(size_t)r * Hz + k0 + BK + c4 * 4];
            }
#pragma unroll
            for (int p = 0; p < 3; ++p) {
                int j = tid + p * K2_T, c = j >> 4, q = j & 15;
                rv[p] = *(const float4*)&V[(size_t)c * Hz + k0 + BK + q * 4];
            }
        }
        // compute from LDS
#pragma unroll
        for (int kk = 0; kk < BK; kk += 4) {
            float4 a0 = *(const float4*)&at[rg +  0][kk];
            float4 a1 = *(const float4*)&at[rg + 32][kk];
            float4 a2 = *(const float4*)&at[rg + 64][kk];
            float4 a3 = *(const float4*)&at[rg + 96][kk];
            float4 v0 = *(const float4*)&vt[colg * 6 + 0][kk];
            float4 v1 = *(const float4*)&vt[colg * 6 + 1][kk];
            float4 v2 = *(const float4*)&vt[colg * 6 + 2][kk];
            float4 v3 = *(const float4*)&vt[colg * 6 + 3][kk];
            float4 v4 = *(const float4*)&vt[colg * 6 + 4][kk];
            float4 v5 = *(const float4*)&vt[colg * 6 + 5][kk];
#define DOT(ACC, AV, VV) ACC = fmaf(AV.w, VV.w, fmaf(AV.z, VV.z, fmaf(AV.y, VV.y, fmaf(AV.x, VV.x, ACC))))
#define ROW(r, AV) \
            DOT(acc[r][0], AV, v0); DOT(acc[r][1], AV, v1); DOT(acc[r][2], AV, v2); \
            DOT(acc[r][3], AV, v3); DOT(acc[r][4], AV, v4); DOT(acc[r][5], AV, v5);
            ROW(0, a0) ROW(1, a1) ROW(2, a2) ROW(3, a3)
#undef ROW
#undef DOT
        }
        __syncthreads();
    }
    // local online-softmax over this thread's 4 rows, combine over 32 row-groups
#pragma unroll
    for (int j = 0; j < 6; ++j) {
        int c = colg * 6 + j;
        float m = fmaxf(fmaxf(acc[0][j], acc[1][j]), fmaxf(acc[2][j], acc[3][j]));
        float s = expf(acc[0][j] - m) + expf(acc[1][j] - m) +
                  expf(acc[2][j] - m) + expf(acc[3][j] - m);
        red_m[c][rg] = m;
        red_s[c][rg] = s;
    }
    __syncthreads();
    if (tid < NCOL) {
        int c = tid;
        float m = red_m[c][0];
        for (int r = 1; r < 32; ++r) m = fmaxf(m, red_m[c][r]);
        float s = 0.f;
        for (int r = 0; r < 32; ++r) s += red_s[c][r] * expf(red_m[c][r] - m);
        pm[((size_t)b * NCOL + c) * NCHUNK + ch] = m;
        ps[((size_t)b * NCOL + c) * NCHUNK + ch] = s;
    }
}

// ---------------- kernel 3: picked logits (dot at the target row) ----------------
__global__ void k3_picked(const float* __restrict__ seq, const float* __restrict__ v,
                          const int* __restrict__ kps, float* __restrict__ picked) {
    int i = blockIdx.x;                    // 0..383
    int b = i / Tz, t = i % Tz;
    int lane = threadIdx.x;                // 64
    for (int k = 0; k < 2; ++k) {
        int tgt  = kps[2 * i + k];
        int safe = min(max(tgt, 0), Lz - 1);
        const float* srow = seq + ((size_t)b * Lz + safe) * Hz;
        const float* vcol = v + ((size_t)(b * NCOL + t * 2 + k)) * Hz;
        float sum = 0.f;
#pragma unroll
        for (int q = 0; q < Hz / 64; ++q) {
            int z = lane + q * 64;
            sum = fmaf(srow[z], vcol[z], sum);
        }
        for (int o = 32; o > 0; o >>= 1) sum += __shfl_down(sum, o, 64);
        if (lane == 0) picked[b * NCOL + t * 2 + k] = sum;
    }
}

// ---------------- kernel 4: combine partials -> ce -> masked-mean loss ----------------
__global__ void k4_final(const int* __restrict__ midx, const int* __restrict__ turns,
                         const int* __restrict__ kps,
                         const float* __restrict__ pm, const float* __restrict__ ps,
                         const float* __restrict__ picked, float* __restrict__ out) {
    int tid = threadIdx.x;                 // 384 threads, one per (b,t)
    int i = tid;
    int b = i / Tz, t = i % Tz;
    int e = midx[i];
    float modm  = (e != EMPTYIDX) ? 1.f : 0.f;
    float tmask = (turns[2 * i] >= 0) ? 1.f : 0.f;
    float ce[2];
#pragma unroll
    for (int k = 0; k < 2; ++k) {
        int c = t * 2 + k;
        const float* pmr = pm + ((size_t)b * NCOL + c) * NCHUNK;
        const float* psr = ps + ((size_t)b * NCOL + c) * NCHUNK;
        float m = pmr[0];
        for (int chn = 1; chn < NCHUNK; ++chn) m = fmaxf(m, pmr[chn]);
        float s = 0.f;
        for (int chn = 0; chn < NCHUNK; ++chn) s += psr[chn] * expf(pmr[chn] - m);
        float lse = m + logf(s);
        int tgt = kps[2 * i + k];
        ce[k] = (tgt >= 0) ? (lse - picked[b * NCOL + c]) : 0.f;
    }
    float contrib = 0.5f * (ce[0] + ce[1]) * modm * tmask;

    __shared__ float wsum[6], wmask[6];
    float sl = contrib, sm = tmask;
    for (int o = 32; o > 0; o >>= 1) {
        sl += __shfl_down(sl, o, 64);
        sm += __shfl_down(sm, o, 64);
    }
    int w = tid >> 6, lane = tid & 63;
    if (lane == 0) { wsum[w] = sl; wmask[w] = sm; }
    __syncthreads();
    if (tid == 0) {
        float a = 0.f, mk = 0.f;
        for (int ww = 0; ww < 6; ++ww) { a += wsum[ww]; mk += wmask[ww]; }
        out[0] = a / mk;
    }
}

extern "C" void kernel_launch(void* const* d_in, const int* in_sizes, int n_in,
                              void* d_out, int out_size, void* d_ws, size_t ws_size,
                              hipStream_t stream) {
    const float* seq   = (const float*)d_in[0];  // (32,2048,768)
    const float* W     = (const float*)d_in[1];  // (7,768,768)
    const float* spanw = (const float*)d_in[2];  // (7,768,2)
    const int*   turns = (const int*)d_in[3];    // (32,12,2)
    const int*   kps   = (const int*)d_in[4];    // (32,12,2)
    const int*   midx  = (const int*)d_in[5];    // (32,12)
    float* out = (float*)d_out;

    char* ws = (char*)d_ws;
    float* cW     = (float*)(ws + 0);                  // 384*768 f32   = 1,179,648 B
    float* v      = (float*)(ws + 1179648);            // 32*24*768 f32 = 2,359,296 B
    float* pm     = (float*)(ws + 1179648 + 2359296);               // 49,152 B
    float* ps     = (float*)(ws + 1179648 + 2359296 + 49152);       // 49,152 B
    float* picked = (float*)(ws + 1179648 + 2359296 + 98304);       // 3,072 B

    hipMemsetAsync(cW, 0, (size_t)384 * Hz * sizeof(float), stream);
    hipLaunchKernelGGL(k1a_cw, dim3(Ez * K1A_ZC * K1A_HC), dim3(256), 0, stream,
                       seq, W, turns, midx, cW);
    hipLaunchKernelGGL(k1b_v, dim3((384 * Hz) / 256), dim3(256), 0, stream,
                       cW, spanw, midx, v);
    hipLaunchKernelGGL(k2_logits, dim3(Bz * NCHUNK), dim3(K2_T), 0, stream, seq, v, pm, ps);
    hipLaunchKernelGGL(k3_picked, dim3(Bz * Tz), dim3(64), 0, stream, seq, v, kps, picked);
    hipLaunchKernelGGL(k4_final, dim3(1), dim3(Bz * Tz), 0, stream,
                       midx, turns, kps, pm, ps, picked, out);
}

// Round 5
// 375.548 us; speedup vs baseline: 1.1414x; 1.1196x over previous
//
#include <hip/hip_runtime.h>
#include <math.h>

#define Bz 32
#define Lz 2048
#define Hz 768
#define Tz 12
#define Ez 7
#define EMPTYIDX 6
#define NCOL 24          // T*2 logit columns per batch
#define LCHUNK 128
#define NCHUNK 16        // Lz / LCHUNK

// ---------------- kernel 1a: cW partial dots, H split across blocks ----------
#define K1A_ZC 3
#define K1A_HB 48
#define K1A_HC 16
__global__ void k1a_cw(const float* __restrict__ seq, const float* __restrict__ W,
                       const int* __restrict__ turns, const int* __restrict__ midx,
                       float* __restrict__ cW) {
    int bx = blockIdx.x;
    int e  = bx % Ez;
    int zc = (bx / Ez) % K1A_ZC;
    int hc = bx / (Ez * K1A_ZC);           // 0..15
    int z  = zc * 256 + threadIdx.x;       // 0..767
    int h0 = hc * K1A_HB;
    int tid = threadIdx.x;

    __shared__ int itemsS[Bz * Tz];
    __shared__ int cntS;
    if (tid == 0) cntS = 0;
    __syncthreads();
    for (int i = tid; i < Bz * Tz; i += 256) {
        int ei = midx[i];
        ei = min(max(ei, 0), Ez - 1);
        if (ei == e) {
            int p = atomicAdd(&cntS, 1);
            itemsS[p] = i;
        }
    }
    __syncthreads();
    int cnt = cntS;

    const float* Wb = W + ((size_t)e * Hz + h0) * Hz + z;
    float w[K1A_HB];
#pragma unroll
    for (int j = 0; j < K1A_HB; ++j) w[j] = Wb[(size_t)j * Hz];

    for (int n = 0; n < cnt; ++n) {
        int i  = itemsS[n];                // block-uniform
        int b  = i / Tz;
        int st = turns[2 * i];
        st = min(max(st, 0), Lz - 1);
        const float* c = seq + ((size_t)(b * Lz + st)) * Hz + h0;  // uniform -> s_load
        float acc = 0.f;
#pragma unroll
        for (int j = 0; j < K1A_HB; ++j) acc = fmaf(c[j], w[j], acc);
        atomicAdd(&cW[(size_t)i * Hz + z], acc);
    }
}

// ---------------- kernel 1b: v = cW * spanw (elementwise) --------------------
__global__ void k1b_v(const float* __restrict__ cW, const float* __restrict__ spanw,
                      const int* __restrict__ midx, float* __restrict__ v) {
    int idx = blockIdx.x * 256 + threadIdx.x;   // 384*768 = 294912
    int i = idx / Hz;
    int z = idx - i * Hz;
    int e = midx[i];
    e = min(max(e, 0), Ez - 1);
    float cw = cW[idx];
    int b = i / Tz, t = i - b * Tz;
    size_t vb = ((size_t)(b * NCOL + t * 2)) * Hz + z;
    v[vb]      = cw * spanw[(e * Hz + z) * 2 + 0];
    v[vb + Hz] = cw * spanw[(e * Hz + z) * 2 + 1];
}

// ---------------- kernel 2: logits GEMM + block logsumexp partials -----------
// grid = Bz*NCHUNK = 512 blocks, 128 threads, BK=64.
// Staging via __builtin_amdgcn_global_load_lds (16B DMA, zero VGPR footprint —
// rounds 3/4 showed register prefetch spills ~200 MB scratch regardless of
// __launch_bounds__). Double-buffered LDS (2 x 77.8/2 KB -> 2 blocks/CU, all
// 512 blocks co-resident); DMA of tile t+1 is in flight during compute of
// tile t; single barrier per tile drains it.
// No-padding constraint of the DMA handled by XOR swizzle: chunk (r, q) of a
// tile lives at float4-index r*16 + (q ^ (r&15)). Compute-read bank groups:
// A: (q^(rg&15))&7 over 16 rg -> each group 2x = free; V rows {j,j+6,j+12,j+18}
// -> keys j+{0,2,4,6} mod 8 -> distinct -> conflict-free.
#define BK 64
#define K2_T 128
#define ACH 2048          // A-tile chunks (128 rows x 16 quads)
#define VCH 384           // V-tile chunks (24 rows x 16 quads)

__device__ __forceinline__ void gl_lds16(const float* g, float4* l) {
    __builtin_amdgcn_global_load_lds(
        (const __attribute__((address_space(1))) void*)g,
        (__attribute__((address_space(3))) void*)l, 16, 0, 0);
}

__global__ void __launch_bounds__(K2_T, 1)
k2_logits(const float* __restrict__ seq, const float* __restrict__ v,
          float* __restrict__ pm, float* __restrict__ ps) {
    int bx = blockIdx.x;
    int b  = bx / NCHUNK;
    int ch = bx % NCHUNK;
    int l0 = ch * LCHUNK;
    int tid = threadIdx.x;
    int rg   = tid >> 2;                   // 0..31 -> rows rg + 32*r
    int colg = tid & 3;                    // 0..3  -> cols colg*6..colg*6+5

    __shared__ float4 lds[2][ACH + VCH];   // 77,824 B

    float acc[4][6];
#pragma unroll
    for (int r = 0; r < 4; ++r)
#pragma unroll
        for (int j = 0; j < 6; ++j) acc[r][j] = 0.f;

    const float* A = seq + ((size_t)b * Lz + l0) * Hz;
    const float* V = v + (size_t)b * NCOL * Hz;

    // DMA one K-tile (k0) into lds[pb]
#define DMA_TILE(pb, k0)                                                     \
    {                                                                        \
        float4* atb = &lds[pb][0];                                           \
        float4* vtb = &lds[pb][ACH];                                         \
        _Pragma("unroll")                                                    \
        for (int p = 0; p < 16; ++p) {                                       \
            int c = p * K2_T + tid;                                          \
            int r = c >> 4;                                                  \
            int q = (c & 15) ^ (r & 15);                                     \
            gl_lds16(&A[(size_t)r * Hz + (k0) + q * 4], atb + c);            \
        }                                                                    \
        _Pragma("unroll")                                                    \
        for (int p = 0; p < 3; ++p) {                                        \
            int c = p * K2_T + tid;                                          \
            int r = c >> 4;                                                  \
            int q = (c & 15) ^ (r & 15);                                     \
            gl_lds16(&V[(size_t)r * Hz + (k0) + q * 4], vtb + c);            \
        }                                                                    \
    }

    DMA_TILE(0, 0)

    int rx = rg & 15;                      // XOR key, same for all 4 A-rows
    int cr0 = colg * 6;
    for (int t = 0; t < Hz / BK; ++t) {
        __syncthreads();                   // implicit vmcnt(0): tile t landed
        if (t + 1 < Hz / BK) {
            int nb = (t + 1) & 1;
            int nk = (t + 1) * BK;
            if (nb) { DMA_TILE(1, nk) } else { DMA_TILE(0, nk) }
        }
        const float4* at4 = &lds[t & 1][0];
        const float4* vt4 = &lds[t & 1][ACH];
#pragma unroll
        for (int q = 0; q < 16; ++q) {
            float4 a0 = at4[(rg +  0) * 16 + (q ^ rx)];
            float4 a1 = at4[(rg + 32) * 16 + (q ^ rx)];
            float4 a2 = at4[(rg + 64) * 16 + (q ^ rx)];
            float4 a3 = at4[(rg + 96) * 16 + (q ^ rx)];
            float4 v0 = vt4[(cr0 + 0) * 16 + (q ^ ((cr0 + 0) & 15))];
            float4 v1 = vt4[(cr0 + 1) * 16 + (q ^ ((cr0 + 1) & 15))];
            float4 v2 = vt4[(cr0 + 2) * 16 + (q ^ ((cr0 + 2) & 15))];
            float4 v3 = vt4[(cr0 + 3) * 16 + (q ^ ((cr0 + 3) & 15))];
            float4 v4 = vt4[(cr0 + 4) * 16 + (q ^ ((cr0 + 4) & 15))];
            float4 v5 = vt4[(cr0 + 5) * 16 + (q ^ ((cr0 + 5) & 15))];
#define DOT(ACC, AV, VV) ACC = fmaf(AV.w, VV.w, fmaf(AV.z, VV.z, fmaf(AV.y, VV.y, fmaf(AV.x, VV.x, ACC))))
#define ROW(r, AV) \
            DOT(acc[r][0], AV, v0); DOT(acc[r][1], AV, v1); DOT(acc[r][2], AV, v2); \
            DOT(acc[r][3], AV, v3); DOT(acc[r][4], AV, v4); DOT(acc[r][5], AV, v5);
            ROW(0, a0) ROW(1, a1) ROW(2, a2) ROW(3, a3)
#undef ROW
#undef DOT
        }
    }
    __syncthreads();
    // reuse LDS for the reduction scratch (done with tiles)
    float* red_m = (float*)&lds[0][0];     // NCOL*33 floats
    float* red_s = red_m + NCOL * 33;
    // local online-softmax over this thread's 4 rows, combine over 32 row-groups
#pragma unroll
    for (int j = 0; j < 6; ++j) {
        int c = cr0 + j;
        float m = fmaxf(fmaxf(acc[0][j], acc[1][j]), fmaxf(acc[2][j], acc[3][j]));
        float s = expf(acc[0][j] - m) + expf(acc[1][j] - m) +
                  expf(acc[2][j] - m) + expf(acc[3][j] - m);
        red_m[c * 33 + rg] = m;
        red_s[c * 33 + rg] = s;
    }
    __syncthreads();
    if (tid < NCOL) {
        int c = tid;
        float m = red_m[c * 33];
        for (int r = 1; r < 32; ++r) m = fmaxf(m, red_m[c * 33 + r]);
        float s = 0.f;
        for (int r = 0; r < 32; ++r) s += red_s[c * 33 + r] * expf(red_m[c * 33 + r] - m);
        pm[((size_t)b * NCOL + c) * NCHUNK + ch] = m;
        ps[((size_t)b * NCOL + c) * NCHUNK + ch] = s;
    }
}

// ---------------- kernel 3: picked logits (dot at the target row) ----------------
__global__ void k3_picked(const float* __restrict__ seq, const float* __restrict__ v,
                          const int* __restrict__ kps, float* __restrict__ picked) {
    int i = blockIdx.x;                    // 0..383
    int b = i / Tz, t = i % Tz;
    int lane = threadIdx.x;                // 64
    for (int k = 0; k < 2; ++k) {
        int tgt  = kps[2 * i + k];
        int safe = min(max(tgt, 0), Lz - 1);
        const float* srow = seq + ((size_t)b * Lz + safe) * Hz;
        const float* vcol = v + ((size_t)(b * NCOL + t * 2 + k)) * Hz;
        float sum = 0.f;
#pragma unroll
        for (int q = 0; q < Hz / 64; ++q) {
            int z = lane + q * 64;
            sum = fmaf(srow[z], vcol[z], sum);
        }
        for (int o = 32; o > 0; o >>= 1) sum += __shfl_down(sum, o, 64);
        if (lane == 0) picked[b * NCOL + t * 2 + k] = sum;
    }
}

// ---------------- kernel 4: combine partials -> ce -> masked-mean loss ----------------
__global__ void k4_final(const int* __restrict__ midx, const int* __restrict__ turns,
                         const int* __restrict__ kps,
                         const float* __restrict__ pm, const float* __restrict__ ps,
                         const float* __restrict__ picked, float* __restrict__ out) {
    int tid = threadIdx.x;                 // 384 threads, one per (b,t)
    int i = tid;
    int b = i / Tz, t = i % Tz;
    int e = midx[i];
    float modm  = (e != EMPTYIDX) ? 1.f : 0.f;
    float tmask = (turns[2 * i] >= 0) ? 1.f : 0.f;
    float ce[2];
#pragma unroll
    for (int k = 0; k < 2; ++k) {
        int c = t * 2 + k;
        const float* pmr = pm + ((size_t)b * NCOL + c) * NCHUNK;
        const float* psr = ps + ((size_t)b * NCOL + c) * NCHUNK;
        float m = pmr[0];
        for (int chn = 1; chn < NCHUNK; ++chn) m = fmaxf(m, pmr[chn]);
        float s = 0.f;
        for (int chn = 0; chn < NCHUNK; ++chn) s += psr[chn] * expf(pmr[chn] - m);
        float lse = m + logf(s);
        int tgt = kps[2 * i + k];
        ce[k] = (tgt >= 0) ? (lse - picked[b * NCOL + c]) : 0.f;
    }
    float contrib = 0.5f * (ce[0] + ce[1]) * modm * tmask;

    __shared__ float wsum[6], wmask[6];
    float sl = contrib, sm = tmask;
    for (int o = 32; o > 0; o >>= 1) {
        sl += __shfl_down(sl, o, 64);
        sm += __shfl_down(sm, o, 64);
    }
    int w = tid >> 6, lane = tid & 63;
    if (lane == 0) { wsum[w] = sl; wmask[w] = sm; }
    __syncthreads();
    if (tid == 0) {
        float a = 0.f, mk = 0.f;
        for (int ww = 0; ww < 6; ++ww) { a += wsum[ww]; mk += wmask[ww]; }
        out[0] = a / mk;
    }
}

extern "C" void kernel_launch(void* const* d_in, const int* in_sizes, int n_in,
                              void* d_out, int out_size, void* d_ws, size_t ws_size,
                              hipStream_t stream) {
    const float* seq   = (const float*)d_in[0];  // (32,2048,768)
    const float* W     = (const float*)d_in[1];  // (7,768,768)
    const float* spanw = (const float*)d_in[2];  // (7,768,2)
    const int*   turns = (const int*)d_in[3];    // (32,12,2)
    const int*   kps   = (const int*)d_in[4];    // (32,12,2)
    const int*   midx  = (const int*)d_in[5];    // (32,12)
    float* out = (float*)d_out;

    char* ws = (char*)d_ws;
    float* cW     = (float*)(ws + 0);                  // 384*768 f32   = 1,179,648 B
    float* v      = (float*)(ws + 1179648);            // 32*24*768 f32 = 2,359,296 B
    float* pm     = (float*)(ws + 1179648 + 2359296);               // 49,152 B
    float* ps     = (float*)(ws + 1179648 + 2359296 + 49152);       // 49,152 B
    float* picked = (float*)(ws + 1179648 + 2359296 + 98304);       // 3,072 B

    hipMemsetAsync(cW, 0, (size_t)384 * Hz * sizeof(float), stream);
    hipLaunchKernelGGL(k1a_cw, dim3(Ez * K1A_ZC * K1A_HC), dim3(256), 0, stream,
                       seq, W, turns, midx, cW);
    hipLaunchKernelGGL(k1b_v, dim3((384 * Hz) / 256), dim3(256), 0, stream,
                       cW, spanw, midx, v);
    hipLaunchKernelGGL(k2_logits, dim3(Bz * NCHUNK), dim3(K2_T), 0, stream, seq, v, pm, ps);
    hipLaunchKernelGGL(k3_picked, dim3(Bz * Tz), dim3(64), 0, stream, seq, v, kps, picked);
    hipLaunchKernelGGL(k4_final, dim3(1), dim3(Bz * Tz), 0, stream,
                       midx, turns, kps, pm, ps, picked, out);
}